// Round 9
// baseline (377.783 us; speedup 1.0000x reference)
//
#include <hip/hip_runtime.h>
#include <cstdint>

#define NN 8192
#define EE 131072
#define EPAD (EE + NN)   // edges + self loops = 139264
#define FIN 128
#define CH 512           // H*HID = H*OUT
#define NH 8
#define NEG 0.2f

typedef __attribute__((ext_vector_type(8))) short short8;
typedef __attribute__((ext_vector_type(4))) short s16x4;
typedef __attribute__((ext_vector_type(4))) float f32x4;

__device__ inline unsigned short bf16rne(float x) {
    unsigned u = __float_as_uint(x);
    unsigned r = (u + 0x7FFFu + ((u >> 16) & 1u)) >> 16;
    return (unsigned short)r;
}
__device__ inline float bf16tof(unsigned short h) {
    return __uint_as_float((unsigned)h << 16);
}
__device__ inline void gload16(const void* g, void* l) {
    __builtin_amdgcn_global_load_lds((const __attribute__((address_space(1))) void*)g,
                                     (__attribute__((address_space(3))) void*)l, 16, 0, 0);
}

// ---------- CSR build ----------

__global__ __launch_bounds__(256) void k_deg(const int* __restrict__ ei, int* __restrict__ deg) {
    int e = blockIdx.x * 256 + threadIdx.x;
    if (e >= EPAD) return;
    int dst = (e < EE) ? ei[EE + e] : (e - EE);
    atomicAdd(&deg[dst], 1);
}

__global__ __launch_bounds__(1024) void k_scan(const int* __restrict__ deg, int* __restrict__ rowptr) {
    __shared__ int part[1024];
    int t = threadIdx.x;
    int loc[8];
    int s = 0;
#pragma unroll
    for (int i = 0; i < 8; i++) { loc[i] = s; s += deg[t * 8 + i]; }
    part[t] = s;
    __syncthreads();
    if (t == 0) {
        int run = 0;
        for (int i = 0; i < 1024; i++) { int tmp = part[i]; part[i] = run; run += tmp; }
        rowptr[NN] = run;
    }
    __syncthreads();
    int base = part[t];
#pragma unroll
    for (int i = 0; i < 8; i++) rowptr[t * 8 + i] = base + loc[i];
}

__global__ __launch_bounds__(256) void k_scatter(const int* __restrict__ ei, const int* __restrict__ rowptr,
                                                 int* __restrict__ cursor, int* __restrict__ ssrc) {
    int e = blockIdx.x * 256 + threadIdx.x;
    if (e >= EPAD) return;
    int src = (e < EE) ? ei[e] : (e - EE);
    int dst = (e < EE) ? ei[EE + e] : (e - EE);
    int pos = rowptr[dst] + atomicAdd(&cursor[dst], 1);
    ssrc[pos] = src;
}

// ---------- conversions ----------

__global__ __launch_bounds__(256) void k_cvt_ah(const float* __restrict__ F,
                                                unsigned short* __restrict__ Ah, int n4) {
    int i = blockIdx.x * 256 + threadIdx.x;
    if (i >= n4) return;
    f32x4 v = ((const f32x4*)F)[i];
#pragma unroll
    for (int c = 0; c < 4; c++) Ah[i * 4 + c] = bf16rne(v[c]);
}

// W[K][512] (Wl,Wr) -> Wt[n=1024][K] hi/lo (transposed, K contiguous)
template <int K>
__global__ __launch_bounds__(256) void k_cvt_w(const float* __restrict__ Wl, const float* __restrict__ Wr,
                                               unsigned short* __restrict__ Wh, unsigned short* __restrict__ Wlo) {
    int idx = blockIdx.x * 256 + threadIdx.x;   // = n*K + k
    int n = idx / K, k = idx % K;
    const float* W = (n < 512) ? Wl : Wr;
    float x = W[k * 512 + (n & 511)];
    unsigned short h = bf16rne(x);
    Wh[idx] = h;
    Wlo[idx] = bf16rne(x - bf16tof(h));
}

// ---------- split-bf16 MFMA GEMM: [8192 x K] @ [K x 1024] -> XL|XR ----------
// A in bf16-hi only; B in hi+lo (2 MFMA/frag): Ah*(Bh+Bl) ~ A_fp32 * B_fp32.

template <int K>
__global__ __launch_bounds__(256) void k_gemm_mfma(const unsigned short* __restrict__ Ah,
                                                   const unsigned short* __restrict__ Bh,
                                                   const unsigned short* __restrict__ Bl,
                                                   float* __restrict__ XL, float* __restrict__ XR) {
    __shared__ unsigned short sAh[4][128][8], sBh[4][128][8], sBl[4][128][8];
    int tid = threadIdx.x;
    int l = tid & 63;
    int w = tid >> 6, wm = w >> 1, wn = w & 1;
    int m0 = blockIdx.x * 128, n0 = blockIdx.y * 128;
    int lr = l & 15, kh = l >> 4;
    f32x4 acc[4][4] = {};

    for (int k0 = 0; k0 < K; k0 += 32) {
#pragma unroll
        for (int g = 0; g < 2; g++) {
            int cell = g * 256 + tid;
            int ckh = cell >> 7, cr = cell & 127;
            int ka = k0 + ckh * 8;
            gload16(Ah + (size_t)(m0 + cr) * K + ka, &sAh[ckh][cr][0]);
            gload16(Bh + (size_t)(n0 + cr) * K + ka, &sBh[ckh][cr][0]);
            gload16(Bl + (size_t)(n0 + cr) * K + ka, &sBl[ckh][cr][0]);
        }
        __syncthreads();
        short8 fah[4], fbh[4], fbl[4];
#pragma unroll
        for (int i = 0; i < 4; i++) {
            fah[i] = *(const short8*)&sAh[kh][wm * 64 + i * 16 + lr][0];
            fbh[i] = *(const short8*)&sBh[kh][wn * 64 + i * 16 + lr][0];
            fbl[i] = *(const short8*)&sBl[kh][wn * 64 + i * 16 + lr][0];
        }
#pragma unroll
        for (int i = 0; i < 4; i++)
#pragma unroll
            for (int j = 0; j < 4; j++) {
                acc[i][j] = __builtin_amdgcn_mfma_f32_16x16x32_bf16(fah[i], fbl[j], acc[i][j], 0, 0, 0);
                acc[i][j] = __builtin_amdgcn_mfma_f32_16x16x32_bf16(fah[i], fbh[j], acc[i][j], 0, 0, 0);
            }
        __syncthreads();
    }
    // C/D layout: col = lane&15, row = (lane>>4)*4 + q  [m89-verified]
    int colt = n0 + wn * 64;
    float* O = (colt < 512) ? XL : XR;
    int cb = colt & 511;
#pragma unroll
    for (int i = 0; i < 4; i++) {
        int mg = m0 + wm * 64 + i * 16 + kh * 4;
#pragma unroll
        for (int j = 0; j < 4; j++) {
            int cg = cb + j * 16 + lr;
#pragma unroll
            for (int q = 0; q < 4; q++)
                O[(size_t)(mg + q) * CH + cg] = acc[i][j][q];
        }
    }
}

// ---------- fused per-node: logits + online softmax + aggregation ----------
// 2 waves per node (head-group g in {0,1}). Lane l owns 4 CONSECUTIVE
// channels g*256 + l*4 .. +3, all in head g*4 + (l>>4):
//  - gather = one float4 per edge per lane (fully coalesced 1KB/wave)
//  - logit fold = in-lane sum of 4, then xor 1/2/4/8 within the 16-lane
//    head group (4 DS ops/edge, chains of the 4-edge chunk independent)
//  - softmax weight p lands in the lanes owning that head's channels:
//    no broadcasts at all; mh/sh/acc are plain per-lane state
//  - defer-rescale (THR=8): rescale only when mc > mh+8; p <= e^8, fp32-safe
// Tail edges masked via z=-1e30 (p=0); ssrc index clamped to beg.

#define LDCHUNK(cb, CX)                                                        \
  {                                                                            \
    int s0 = ssrc[(cb)];                                                       \
    int s1 = ssrc[((cb) + 1 < end) ? (cb) + 1 : beg];                          \
    int s2 = ssrc[((cb) + 2 < end) ? (cb) + 2 : beg];                          \
    int s3 = ssrc[((cb) + 3 < end) ? (cb) + 3 : beg];                          \
    CX[0] = *(const f32x4*)(XLg + (size_t)s0 * CH);                            \
    CX[1] = *(const f32x4*)(XLg + (size_t)s1 * CH);                            \
    CX[2] = *(const f32x4*)(XLg + (size_t)s2 * CH);                            \
    CX[3] = *(const f32x4*)(XLg + (size_t)s3 * CH);                            \
  }

#define PROCESS(CX, cb)                                                        \
  {                                                                            \
    float z[4];                                                                \
    _Pragma("unroll") for (int e = 0; e < 4; e++) {                            \
      float s = 0.f;                                                           \
      _Pragma("unroll") for (int r = 0; r < 4; r++) {                          \
        float t = CX[e][r] + xrv[r];                                           \
        t = (t > 0.f) ? t : NEG * t;                                           \
        s += t * atv[r];                                                       \
      }                                                                        \
      z[e] = s;                                                                \
    }                                                                          \
    _Pragma("unroll") for (int m = 1; m <= 8; m <<= 1)                         \
      _Pragma("unroll") for (int e = 0; e < 4; e++)                            \
        z[e] += __shfl_xor(z[e], m);                                           \
    _Pragma("unroll") for (int e = 1; e < 4; e++)                              \
      if ((cb) + e >= end) z[e] = -1e30f;                                      \
    float mc = fmaxf(fmaxf(z[0], z[1]), fmaxf(z[2], z[3]));                    \
    if (__ballot(mc > mh + 8.f) == 0ULL) {                                     \
      float p0 = __expf(z[0] - mh), p1 = __expf(z[1] - mh);                    \
      float p2 = __expf(z[2] - mh), p3 = __expf(z[3] - mh);                    \
      sh += (p0 + p1) + (p2 + p3);                                             \
      _Pragma("unroll") for (int r = 0; r < 4; r++)                            \
        acc[r] += p0 * CX[0][r] + p1 * CX[1][r] + p2 * CX[2][r] +              \
                  p3 * CX[3][r];                                               \
    } else {                                                                   \
      float nm = fmaxf(mh, mc);                                                \
      float sc = __expf(mh - nm);                                              \
      float p0 = __expf(z[0] - nm), p1 = __expf(z[1] - nm);                    \
      float p2 = __expf(z[2] - nm), p3 = __expf(z[3] - nm);                    \
      sh = sh * sc + (p0 + p1) + (p2 + p3);                                    \
      mh = nm;                                                                 \
      _Pragma("unroll") for (int r = 0; r < 4; r++)                            \
        acc[r] = acc[r] * sc + p0 * CX[0][r] + p1 * CX[1][r] +                 \
                 p2 * CX[2][r] + p3 * CX[3][r];                                \
    }                                                                          \
  }

template <int WRITE_BF16>
__global__ __launch_bounds__(256) void k_node3(const float* __restrict__ XL,
                                               const float* __restrict__ XR,
                                               const int* __restrict__ rowptr,
                                               const int* __restrict__ ssrc,
                                               const float* __restrict__ att,
                                               const float* __restrict__ bias,
                                               float* __restrict__ OUT,
                                               unsigned short* __restrict__ OAh) {
    int w = threadIdx.x >> 6;
    int n = blockIdx.x * 2 + (w >> 1);
    int g = w & 1;                       // head-group: heads g*4 .. g*4+3
    int l = threadIdx.x & 63;
    int beg = rowptr[n], end = rowptr[n + 1];
    int hb = g * 256 + l * 4;            // 4 consecutive channels, one head

    const float* XLg = XL + hb;
    f32x4 xrv = *(const f32x4*)(XR + (size_t)n * CH + hb);
    f32x4 atv = *(const f32x4*)(att + hb);
    f32x4 acc = {0.f, 0.f, 0.f, 0.f};
    float mh = -1e30f, sh = 0.f;

    f32x4 curA[4], curB[4];
    LDCHUNK(beg, curA);
    int base = beg;
    while (true) {
        if (base + 4 < end) LDCHUNK(base + 4, curB);
        PROCESS(curA, base);
        base += 4;
        if (base >= end) break;
        if (base + 4 < end) LDCHUNK(base + 4, curA);
        PROCESS(curB, base);
        base += 4;
        if (base >= end) break;
    }

    float inv = 1.f / sh;
    f32x4 biasv = *(const f32x4*)(bias + hb);
    size_t ob = (size_t)n * CH + hb;
    if (WRITE_BF16) {
        s16x4 hv;
#pragma unroll
        for (int r = 0; r < 4; r++) {
            float wv = acc[r] * inv + biasv[r];
            hv[r] = (short)bf16rne(wv);
        }
        *(s16x4*)(OAh + ob) = hv;
    } else {
        f32x4 ov;
#pragma unroll
        for (int r = 0; r < 4; r++) {
            float wv = acc[r] * inv + biasv[r];
            ov[r] = (wv > 0.f) ? wv : (__expf(wv) - 1.f);
        }
        *(f32x4*)(OUT + ob) = ov;
    }
}

// ---------- host ----------

extern "C" void kernel_launch(void* const* d_in, const int* in_sizes, int n_in,
                              void* d_out, int out_size, void* d_ws, size_t ws_size,
                              hipStream_t stream) {
    const float* x    = (const float*)d_in[0];
    const int*   ei   = (const int*)d_in[1];
    const float* W1l  = (const float*)d_in[2];
    const float* W1r  = (const float*)d_in[3];
    const float* att1 = (const float*)d_in[4];
    const float* b1   = (const float*)d_in[5];
    const float* W2l  = (const float*)d_in[6];
    const float* W2r  = (const float*)d_in[7];
    const float* att2 = (const float*)d_in[8];
    const float* b2   = (const float*)d_in[9];
    float* out = (float*)d_out;

    char* ws = (char*)d_ws;
    int* rowptr = (int*)ws;                 // NN+1
    int* cursor = rowptr + NN + 1;          // NN
    int* deg    = cursor + NN;              // NN
    int* ssrc   = deg + NN;                 // EPAD
    float* XL = (float*)(((uintptr_t)(ssrc + EPAD) + 255) & ~(uintptr_t)255);
    float* XR = XL + (size_t)NN * CH;
    unsigned short* A_h = (unsigned short*)(XR + (size_t)NN * CH);  // NN*CH bf16
    unsigned short* W1h = A_h + (size_t)NN * CH;   // 1024*FIN
    unsigned short* W1o = W1h + 1024 * FIN;
    unsigned short* W2h = W1o + 1024 * FIN;        // 1024*CH
    unsigned short* W2o = W2h + 1024 * CH;

    hipMemsetAsync(cursor, 0, (size_t)2 * NN * sizeof(int), stream);
    k_deg<<<(EPAD + 255) / 256, 256, 0, stream>>>(ei, deg);
    k_scan<<<1, 1024, 0, stream>>>(deg, rowptr);
    k_scatter<<<(EPAD + 255) / 256, 256, 0, stream>>>(ei, rowptr, cursor, ssrc);
    k_cvt_w<FIN><<<1024 * FIN / 256, 256, 0, stream>>>(W1l, W1r, W1h, W1o);
    k_cvt_w<CH><<<1024 * CH / 256, 256, 0, stream>>>(W2l, W2r, W2h, W2o);

    for (int b = 0; b < 2; b++) {
        const float* f = x + (size_t)b * NN * FIN;
        k_cvt_ah<<<NN * FIN / 4 / 256, 256, 0, stream>>>(f, A_h, NN * FIN / 4);
        k_gemm_mfma<FIN><<<dim3(NN / 128, 8), 256, 0, stream>>>(A_h, W1h, W1o, XL, XR);
        k_node3<1><<<NN / 2, 256, 0, stream>>>(XL, XR, rowptr, ssrc, att1, b1, nullptr, A_h);
        k_gemm_mfma<CH><<<dim3(NN / 128, 8), 256, 0, stream>>>(A_h, W2h, W2o, XL, XR);
        k_node3<0><<<NN / 2, 256, 0, stream>>>(XL, XR, rowptr, ssrc, att2, b2,
                                               out + (size_t)b * NN * CH, nullptr);
    }
}

// Round 10
// 317.780 us; speedup vs baseline: 1.1888x; 1.1888x over previous
//
#include <hip/hip_runtime.h>
#include <cstdint>

#define NN 8192
#define EE 131072
#define EPAD (EE + NN)   // edges + self loops = 139264
#define FIN 128
#define CH 512           // H*HID = H*OUT
#define NH 8
#define NEG 0.2f

typedef __attribute__((ext_vector_type(8))) short short8;
typedef __attribute__((ext_vector_type(4))) float f32x4;

__device__ inline unsigned short bf16rne(float x) {
    unsigned u = __float_as_uint(x);
    unsigned r = (u + 0x7FFFu + ((u >> 16) & 1u)) >> 16;
    return (unsigned short)r;
}
__device__ inline float bf16tof(unsigned short h) {
    return __uint_as_float((unsigned)h << 16);
}
__device__ inline void gload16(const void* g, void* l) {
    __builtin_amdgcn_global_load_lds((const __attribute__((address_space(1))) void*)g,
                                     (__attribute__((address_space(3))) void*)l, 16, 0, 0);
}
// broadcast lane's float via v_readlane (VALU, no DS-crossbar traffic)
#define RLF(x, lane) __int_as_float(__builtin_amdgcn_readlane(__float_as_int(x), (lane)))

// ---------- CSR build ----------

__global__ __launch_bounds__(256) void k_deg(const int* __restrict__ ei, int* __restrict__ deg) {
    int e = blockIdx.x * 256 + threadIdx.x;
    if (e >= EPAD) return;
    int dst = (e < EE) ? ei[EE + e] : (e - EE);
    atomicAdd(&deg[dst], 1);
}

__global__ __launch_bounds__(1024) void k_scan(const int* __restrict__ deg, int* __restrict__ rowptr) {
    __shared__ int part[1024];
    int t = threadIdx.x;
    int loc[8];
    int s = 0;
#pragma unroll
    for (int i = 0; i < 8; i++) { loc[i] = s; s += deg[t * 8 + i]; }
    part[t] = s;
    __syncthreads();
    if (t == 0) {
        int run = 0;
        for (int i = 0; i < 1024; i++) { int tmp = part[i]; part[i] = run; run += tmp; }
        rowptr[NN] = run;
    }
    __syncthreads();
    int base = part[t];
#pragma unroll
    for (int i = 0; i < 8; i++) rowptr[t * 8 + i] = base + loc[i];
}

__global__ __launch_bounds__(256) void k_scatter(const int* __restrict__ ei, const int* __restrict__ rowptr,
                                                 int* __restrict__ cursor, int* __restrict__ ssrc) {
    int e = blockIdx.x * 256 + threadIdx.x;
    if (e >= EPAD) return;
    int src = (e < EE) ? ei[e] : (e - EE);
    int dst = (e < EE) ? ei[EE + e] : (e - EE);
    int pos = rowptr[dst] + atomicAdd(&cursor[dst], 1);
    ssrc[pos] = src;
}

// ---------- conversions ----------

__global__ __launch_bounds__(256) void k_cvt_ah(const float* __restrict__ F,
                                                unsigned short* __restrict__ Ah, int n4) {
    int i = blockIdx.x * 256 + threadIdx.x;
    if (i >= n4) return;
    f32x4 v = ((const f32x4*)F)[i];
#pragma unroll
    for (int c = 0; c < 4; c++) Ah[i * 4 + c] = bf16rne(v[c]);
}

// W[K][512] (Wl,Wr) -> Wt[n=1024][K] hi/lo (transposed, K contiguous)
template <int K>
__global__ __launch_bounds__(256) void k_cvt_w(const float* __restrict__ Wl, const float* __restrict__ Wr,
                                               unsigned short* __restrict__ Wh, unsigned short* __restrict__ Wlo) {
    int idx = blockIdx.x * 256 + threadIdx.x;   // = n*K + k
    int n = idx / K, k = idx % K;
    const float* W = (n < 512) ? Wl : Wr;
    float x = W[k * 512 + (n & 511)];
    unsigned short h = bf16rne(x);
    Wh[idx] = h;
    Wlo[idx] = bf16rne(x - bf16tof(h));
}

// ---------- split-bf16 MFMA GEMM: [8192 x K] @ [K x 1024] -> XLb (bf16) | XR (f32) ----------
// A in bf16-hi only; B in hi+lo (2 MFMA/frag): Ah*(Bh+Bl) ~ A_fp32 * B_fp32.
// L-half of the output is stored as bf16 (gather path reads it bf16).

template <int K>
__global__ __launch_bounds__(256) void k_gemm_mfma(const unsigned short* __restrict__ Ah,
                                                   const unsigned short* __restrict__ Bh,
                                                   const unsigned short* __restrict__ Bl,
                                                   unsigned short* __restrict__ XLb,
                                                   float* __restrict__ XR) {
    __shared__ unsigned short sAh[4][128][8], sBh[4][128][8], sBl[4][128][8];
    int tid = threadIdx.x;
    int l = tid & 63;
    int w = tid >> 6, wm = w >> 1, wn = w & 1;
    int m0 = blockIdx.x * 128, n0 = blockIdx.y * 128;
    int lr = l & 15, kh = l >> 4;
    f32x4 acc[4][4] = {};

    for (int k0 = 0; k0 < K; k0 += 32) {
#pragma unroll
        for (int g = 0; g < 2; g++) {
            int cell = g * 256 + tid;
            int ckh = cell >> 7, cr = cell & 127;
            int ka = k0 + ckh * 8;
            gload16(Ah + (size_t)(m0 + cr) * K + ka, &sAh[ckh][cr][0]);
            gload16(Bh + (size_t)(n0 + cr) * K + ka, &sBh[ckh][cr][0]);
            gload16(Bl + (size_t)(n0 + cr) * K + ka, &sBl[ckh][cr][0]);
        }
        __syncthreads();
        short8 fah[4], fbh[4], fbl[4];
#pragma unroll
        for (int i = 0; i < 4; i++) {
            fah[i] = *(const short8*)&sAh[kh][wm * 64 + i * 16 + lr][0];
            fbh[i] = *(const short8*)&sBh[kh][wn * 64 + i * 16 + lr][0];
            fbl[i] = *(const short8*)&sBl[kh][wn * 64 + i * 16 + lr][0];
        }
#pragma unroll
        for (int i = 0; i < 4; i++)
#pragma unroll
            for (int j = 0; j < 4; j++) {
                acc[i][j] = __builtin_amdgcn_mfma_f32_16x16x32_bf16(fah[i], fbl[j], acc[i][j], 0, 0, 0);
                acc[i][j] = __builtin_amdgcn_mfma_f32_16x16x32_bf16(fah[i], fbh[j], acc[i][j], 0, 0, 0);
            }
        __syncthreads();
    }
    // C/D layout: col = lane&15, row = (lane>>4)*4 + q  [m89-verified]
    int colt = n0 + wn * 64;     // wave-uniform
    int cb = colt & 511;
    if (colt < 512) {
#pragma unroll
        for (int i = 0; i < 4; i++) {
            int mg = m0 + wm * 64 + i * 16 + kh * 4;
#pragma unroll
            for (int j = 0; j < 4; j++) {
                int cg = cb + j * 16 + lr;
#pragma unroll
                for (int q = 0; q < 4; q++)
                    XLb[(size_t)(mg + q) * CH + cg] = bf16rne(acc[i][j][q]);
            }
        }
    } else {
#pragma unroll
        for (int i = 0; i < 4; i++) {
            int mg = m0 + wm * 64 + i * 16 + kh * 4;
#pragma unroll
            for (int j = 0; j < 4; j++) {
                int cg = cb + j * 16 + lr;
#pragma unroll
                for (int q = 0; q < 4; q++)
                    XR[(size_t)(mg + q) * CH + cg] = acc[i][j][q];
            }
        }
    }
}

// ---------- fused per-node: logits + online softmax + aggregation ----------
// 2 waves per node (head-group g in {0,1}, 4 heads each). 4-edge chunks,
// double-buffered. XL gathered as bf16 (half traffic -> ~2x L2 hit rate).
// Joint fold of 16 (edge,head) regs: lane bits 1:0 <- head, bits 3:2 <- edge;
// p broadcasts via v_readlane (0 DS). Defer-rescale THR=8.
// Tail edges masked via logit=-1e30 (p=0).

#define LDCHUNK(cb, CS, CX)                                                    \
  {                                                                            \
    CS[0] = ssrc[(cb)];                                                        \
    CS[1] = ssrc[((cb) + 1 < end) ? (cb) + 1 : beg];                           \
    CS[2] = ssrc[((cb) + 2 < end) ? (cb) + 2 : beg];                           \
    CS[3] = ssrc[((cb) + 3 < end) ? (cb) + 3 : beg];                           \
    _Pragma("unroll") for (int e = 0; e < 4; e++) {                            \
      const unsigned short* _p = XLg + (size_t)CS[e] * CH;                     \
      _Pragma("unroll") for (int r = 0; r < 4; r++)                            \
        CX[e][r] = bf16tof(_p[r * 64]);                                        \
    }                                                                          \
  }

#define PROCESS(CX, cb)                                                        \
  {                                                                            \
    float v[4][4];                                                             \
    _Pragma("unroll") for (int e = 0; e < 4; e++)                              \
      _Pragma("unroll") for (int r = 0; r < 4; r++) {                          \
        float t = CX[e][r] + xr[r];                                            \
        t = (t > 0.f) ? t : NEG * t;                                           \
        v[e][r] = t * at[r];                                                   \
      }                                                                        \
    {                                                                          \
      int b = l & 1; /* head bit0 */                                           \
      _Pragma("unroll") for (int e = 0; e < 4; e++) {                          \
        float k0 = b ? v[e][1] : v[e][0], s0 = b ? v[e][0] : v[e][1];          \
        float k1 = b ? v[e][3] : v[e][2], s1 = b ? v[e][2] : v[e][3];          \
        v[e][0] = k0 + __shfl_xor(s0, 1);                                      \
        v[e][1] = k1 + __shfl_xor(s1, 1);                                      \
      }                                                                        \
    }                                                                          \
    {                                                                          \
      int b = (l >> 1) & 1; /* head bit1 */                                    \
      _Pragma("unroll") for (int e = 0; e < 4; e++) {                          \
        float k0 = b ? v[e][1] : v[e][0], s0 = b ? v[e][0] : v[e][1];          \
        v[e][0] = k0 + __shfl_xor(s0, 2);                                      \
      }                                                                        \
    }                                                                          \
    {                                                                          \
      int b = (l >> 2) & 1; /* edge bit0 */                                    \
      float k0 = b ? v[1][0] : v[0][0], s0 = b ? v[0][0] : v[1][0];            \
      float k1 = b ? v[3][0] : v[2][0], s1 = b ? v[2][0] : v[3][0];            \
      v[0][0] = k0 + __shfl_xor(s0, 4);                                        \
      v[1][0] = k1 + __shfl_xor(s1, 4);                                        \
    }                                                                          \
    float z;                                                                   \
    {                                                                          \
      int b = (l >> 3) & 1; /* edge bit1 */                                    \
      float k0 = b ? v[1][0] : v[0][0], s0 = b ? v[0][0] : v[1][0];            \
      z = k0 + __shfl_xor(s0, 8);                                              \
    }                                                                          \
    z += __shfl_xor(z, 16);                                                    \
    z += __shfl_xor(z, 32);                                                    \
    if ((cb) + ((l >> 2) & 3) >= end) z = -1e30f;                              \
    float mc = fmaxf(z, __shfl_xor(z, 4));                                     \
    mc = fmaxf(mc, __shfl_xor(mc, 8));                                         \
    unsigned long long grow = __ballot(mc > mh + 8.f);                         \
    if (grow == 0ULL) {                                                        \
      float p = __expf(z - mh);                                                \
      float q = p + __shfl_xor(p, 4);                                          \
      q += __shfl_xor(q, 8);                                                   \
      sh += q;                                                                 \
      _Pragma("unroll") for (int r = 0; r < 4; r++) {                          \
        float a2 = acc[r];                                                     \
        a2 += RLF(p, r) * CX[0][r];                                            \
        a2 += RLF(p, 4 + r) * CX[1][r];                                        \
        a2 += RLF(p, 8 + r) * CX[2][r];                                        \
        a2 += RLF(p, 12 + r) * CX[3][r];                                       \
        acc[r] = a2;                                                           \
      }                                                                        \
    } else {                                                                   \
      float nm = fmaxf(mh, mc);                                                \
      float scale = __expf(mh - nm);                                           \
      float p = __expf(z - nm);                                                \
      float q = p + __shfl_xor(p, 4);                                          \
      q += __shfl_xor(q, 8);                                                   \
      sh = sh * scale + q;                                                     \
      mh = nm;                                                                 \
      _Pragma("unroll") for (int r = 0; r < 4; r++) {                          \
        float a2 = acc[r] * RLF(scale, r);                                     \
        a2 += RLF(p, r) * CX[0][r];                                            \
        a2 += RLF(p, 4 + r) * CX[1][r];                                        \
        a2 += RLF(p, 8 + r) * CX[2][r];                                        \
        a2 += RLF(p, 12 + r) * CX[3][r];                                       \
        acc[r] = a2;                                                           \
      }                                                                        \
    }                                                                          \
  }

template <int WRITE_BF16>
__global__ __launch_bounds__(256) void k_node2(const unsigned short* __restrict__ XLb,
                                               const float* __restrict__ XR,
                                               const int* __restrict__ rowptr,
                                               const int* __restrict__ ssrc,
                                               const float* __restrict__ att,
                                               const float* __restrict__ bias,
                                               float* __restrict__ OUT,
                                               unsigned short* __restrict__ OAh) {
    int w = threadIdx.x >> 6;
    int n = blockIdx.x * 2 + (w >> 1);
    int g = w & 1;                       // head-group: heads g*4 .. g*4+3
    int l = threadIdx.x & 63;
    int beg = rowptr[n], end = rowptr[n + 1];
    int hb = g * 256 + l;                // channel base within row

    const unsigned short* XLg = XLb + hb;
    float xr[4], at[4], acc[4];
    const float* pr = XR + (size_t)n * CH + hb;
#pragma unroll
    for (int r = 0; r < 4; r++) {
        xr[r] = pr[r * 64];
        at[r] = att[hb + r * 64];
        acc[r] = 0.f;
    }
    float mh = -1e30f, sh = 0.f;

    int srcA[4], srcB[4];
    float curA[4][4], curB[4][4];
    LDCHUNK(beg, srcA, curA);
    int base = beg;
    while (true) {
        if (base + 4 < end) LDCHUNK(base + 4, srcB, curB);
        PROCESS(curA, base);
        base += 4;
        if (base >= end) break;
        if (base + 4 < end) LDCHUNK(base + 4, srcA, curA);
        PROCESS(curB, base);
        base += 4;
        if (base >= end) break;
    }

    float inv = 1.f / sh;
    size_t obase = (size_t)n * CH + hb;
#pragma unroll
    for (int r = 0; r < 4; r++) {
        float wv = acc[r] * RLF(inv, r) + bias[hb + r * 64];
        if (WRITE_BF16) {
            OAh[obase + r * 64] = bf16rne(wv);
        } else {
            wv = (wv > 0.f) ? wv : (__expf(wv) - 1.f);
            OUT[obase + r * 64] = wv;
        }
    }
}

// ---------- host ----------

extern "C" void kernel_launch(void* const* d_in, const int* in_sizes, int n_in,
                              void* d_out, int out_size, void* d_ws, size_t ws_size,
                              hipStream_t stream) {
    const float* x    = (const float*)d_in[0];
    const int*   ei   = (const int*)d_in[1];
    const float* W1l  = (const float*)d_in[2];
    const float* W1r  = (const float*)d_in[3];
    const float* att1 = (const float*)d_in[4];
    const float* b1   = (const float*)d_in[5];
    const float* W2l  = (const float*)d_in[6];
    const float* W2r  = (const float*)d_in[7];
    const float* att2 = (const float*)d_in[8];
    const float* b2   = (const float*)d_in[9];
    float* out = (float*)d_out;

    char* ws = (char*)d_ws;
    int* rowptr = (int*)ws;                 // NN+1
    int* cursor = rowptr + NN + 1;          // NN
    int* deg    = cursor + NN;              // NN
    int* ssrc   = deg + NN;                 // EPAD
    unsigned short* XLb = (unsigned short*)(((uintptr_t)(ssrc + EPAD) + 255) & ~(uintptr_t)255);
    float* XR = (float*)(XLb + (size_t)NN * CH);
    unsigned short* A_h = (unsigned short*)(XR + (size_t)NN * CH);  // NN*CH bf16
    unsigned short* W1h = A_h + (size_t)NN * CH;   // 1024*FIN
    unsigned short* W1o = W1h + 1024 * FIN;
    unsigned short* W2h = W1o + 1024 * FIN;        // 1024*CH
    unsigned short* W2o = W2h + 1024 * CH;

    hipMemsetAsync(cursor, 0, (size_t)2 * NN * sizeof(int), stream);
    k_deg<<<(EPAD + 255) / 256, 256, 0, stream>>>(ei, deg);
    k_scan<<<1, 1024, 0, stream>>>(deg, rowptr);
    k_scatter<<<(EPAD + 255) / 256, 256, 0, stream>>>(ei, rowptr, cursor, ssrc);
    k_cvt_w<FIN><<<1024 * FIN / 256, 256, 0, stream>>>(W1l, W1r, W1h, W1o);
    k_cvt_w<CH><<<1024 * CH / 256, 256, 0, stream>>>(W2l, W2r, W2h, W2o);

    for (int b = 0; b < 2; b++) {
        const float* f = x + (size_t)b * NN * FIN;
        k_cvt_ah<<<NN * FIN / 4 / 256, 256, 0, stream>>>(f, A_h, NN * FIN / 4);
        k_gemm_mfma<FIN><<<dim3(NN / 128, 8), 256, 0, stream>>>(A_h, W1h, W1o, XLb, XR);
        k_node2<1><<<NN / 2, 256, 0, stream>>>(XLb, XR, rowptr, ssrc, att1, b1, nullptr, A_h);
        k_gemm_mfma<CH><<<dim3(NN / 128, 8), 256, 0, stream>>>(A_h, W2h, W2o, XLb, XR);
        k_node2<0><<<NN / 2, 256, 0, stream>>>(XLb, XR, rowptr, ssrc, att2, b2,
                                               out + (size_t)b * NN * CH, nullptr);
    }
}

// Round 11
// 292.028 us; speedup vs baseline: 1.2937x; 1.0882x over previous
//
#include <hip/hip_runtime.h>
#include <cstdint>

#define NN 8192
#define EE 131072
#define EPAD (EE + NN)   // edges + self loops = 139264
#define FIN 128
#define CH 512           // H*HID = H*OUT
#define NH 8
#define NEG 0.2f

typedef __attribute__((ext_vector_type(8))) short short8;
typedef __attribute__((ext_vector_type(4))) unsigned short u16x4;
typedef __attribute__((ext_vector_type(4))) float f32x4;

__device__ inline unsigned short bf16rne(float x) {
    unsigned u = __float_as_uint(x);
    unsigned r = (u + 0x7FFFu + ((u >> 16) & 1u)) >> 16;
    return (unsigned short)r;
}
__device__ inline float bf16tof(unsigned short h) {
    return __uint_as_float((unsigned)h << 16);
}
__device__ inline void gload16(const void* g, void* l) {
    __builtin_amdgcn_global_load_lds((const __attribute__((address_space(1))) void*)g,
                                     (__attribute__((address_space(3))) void*)l, 16, 0, 0);
}
// cross-lane add via DPP (VALU only, no DS crossbar). CTRL: 0xB1=quad_perm
// xor1, 0x4E=quad_perm xor2, 0x124=row_ror:4, 0x128=row_ror:8.
template <int CTRL>
__device__ inline float dpp_add(float x) {
    int v = __builtin_amdgcn_update_dpp(0, __float_as_int(x), CTRL, 0xF, 0xF, true);
    return x + __int_as_float(v);
}

// ---------- CSR build ----------

__global__ __launch_bounds__(256) void k_deg(const int* __restrict__ ei, int* __restrict__ deg) {
    int e = blockIdx.x * 256 + threadIdx.x;
    if (e >= EPAD) return;
    int dst = (e < EE) ? ei[EE + e] : (e - EE);
    atomicAdd(&deg[dst], 1);
}

__global__ __launch_bounds__(1024) void k_scan(const int* __restrict__ deg, int* __restrict__ rowptr) {
    __shared__ int part[1024];
    int t = threadIdx.x;
    int loc[8];
    int s = 0;
#pragma unroll
    for (int i = 0; i < 8; i++) { loc[i] = s; s += deg[t * 8 + i]; }
    part[t] = s;
    __syncthreads();
    if (t == 0) {
        int run = 0;
        for (int i = 0; i < 1024; i++) { int tmp = part[i]; part[i] = run; run += tmp; }
        rowptr[NN] = run;
    }
    __syncthreads();
    int base = part[t];
#pragma unroll
    for (int i = 0; i < 8; i++) rowptr[t * 8 + i] = base + loc[i];
}

__global__ __launch_bounds__(256) void k_scatter(const int* __restrict__ ei, const int* __restrict__ rowptr,
                                                 int* __restrict__ cursor, int* __restrict__ ssrc) {
    int e = blockIdx.x * 256 + threadIdx.x;
    if (e >= EPAD) return;
    int src = (e < EE) ? ei[e] : (e - EE);
    int dst = (e < EE) ? ei[EE + e] : (e - EE);
    int pos = rowptr[dst] + atomicAdd(&cursor[dst], 1);
    ssrc[pos] = src;
}

// ---------- conversions ----------

__global__ __launch_bounds__(256) void k_cvt_ah(const float* __restrict__ F,
                                                unsigned short* __restrict__ Ah, int n4) {
    int i = blockIdx.x * 256 + threadIdx.x;
    if (i >= n4) return;
    f32x4 v = ((const f32x4*)F)[i];
#pragma unroll
    for (int c = 0; c < 4; c++) Ah[i * 4 + c] = bf16rne(v[c]);
}

// W[K][512] (Wl,Wr) -> Wt[n=1024][K] hi/lo (transposed, K contiguous)
template <int K>
__global__ __launch_bounds__(256) void k_cvt_w(const float* __restrict__ Wl, const float* __restrict__ Wr,
                                               unsigned short* __restrict__ Wh, unsigned short* __restrict__ Wlo) {
    int idx = blockIdx.x * 256 + threadIdx.x;   // = n*K + k
    int n = idx / K, k = idx % K;
    const float* W = (n < 512) ? Wl : Wr;
    float x = W[k * 512 + (n & 511)];
    unsigned short h = bf16rne(x);
    Wh[idx] = h;
    Wlo[idx] = bf16rne(x - bf16tof(h));
}

// ---------- split-bf16 MFMA GEMM: [8192 x K] @ [K x 1024] -> XLb (bf16) | XR (f32) ----------
// A in bf16-hi only; B in hi+lo (2 MFMA/frag): Ah*(Bh+Bl) ~ A_fp32 * B_fp32.

template <int K>
__global__ __launch_bounds__(256) void k_gemm_mfma(const unsigned short* __restrict__ Ah,
                                                   const unsigned short* __restrict__ Bh,
                                                   const unsigned short* __restrict__ Bl,
                                                   unsigned short* __restrict__ XLb,
                                                   float* __restrict__ XR) {
    __shared__ unsigned short sAh[4][128][8], sBh[4][128][8], sBl[4][128][8];
    int tid = threadIdx.x;
    int l = tid & 63;
    int w = tid >> 6, wm = w >> 1, wn = w & 1;
    int m0 = blockIdx.x * 128, n0 = blockIdx.y * 128;
    int lr = l & 15, kh = l >> 4;
    f32x4 acc[4][4] = {};

    for (int k0 = 0; k0 < K; k0 += 32) {
#pragma unroll
        for (int g = 0; g < 2; g++) {
            int cell = g * 256 + tid;
            int ckh = cell >> 7, cr = cell & 127;
            int ka = k0 + ckh * 8;
            gload16(Ah + (size_t)(m0 + cr) * K + ka, &sAh[ckh][cr][0]);
            gload16(Bh + (size_t)(n0 + cr) * K + ka, &sBh[ckh][cr][0]);
            gload16(Bl + (size_t)(n0 + cr) * K + ka, &sBl[ckh][cr][0]);
        }
        __syncthreads();
        short8 fah[4], fbh[4], fbl[4];
#pragma unroll
        for (int i = 0; i < 4; i++) {
            fah[i] = *(const short8*)&sAh[kh][wm * 64 + i * 16 + lr][0];
            fbh[i] = *(const short8*)&sBh[kh][wn * 64 + i * 16 + lr][0];
            fbl[i] = *(const short8*)&sBl[kh][wn * 64 + i * 16 + lr][0];
        }
#pragma unroll
        for (int i = 0; i < 4; i++)
#pragma unroll
            for (int j = 0; j < 4; j++) {
                acc[i][j] = __builtin_amdgcn_mfma_f32_16x16x32_bf16(fah[i], fbl[j], acc[i][j], 0, 0, 0);
                acc[i][j] = __builtin_amdgcn_mfma_f32_16x16x32_bf16(fah[i], fbh[j], acc[i][j], 0, 0, 0);
            }
        __syncthreads();
    }
    // C/D layout: col = lane&15, row = (lane>>4)*4 + q  [m89-verified]
    int colt = n0 + wn * 64;     // wave-uniform
    int cb = colt & 511;
    if (colt < 512) {
#pragma unroll
        for (int i = 0; i < 4; i++) {
            int mg = m0 + wm * 64 + i * 16 + kh * 4;
#pragma unroll
            for (int j = 0; j < 4; j++) {
                int cg = cb + j * 16 + lr;
#pragma unroll
                for (int q = 0; q < 4; q++)
                    XLb[(size_t)(mg + q) * CH + cg] = bf16rne(acc[i][j][q]);
            }
        }
    } else {
#pragma unroll
        for (int i = 0; i < 4; i++) {
            int mg = m0 + wm * 64 + i * 16 + kh * 4;
#pragma unroll
            for (int j = 0; j < 4; j++) {
                int cg = cb + j * 16 + lr;
#pragma unroll
                for (int q = 0; q < 4; q++)
                    XR[(size_t)(mg + q) * CH + cg] = acc[i][j][q];
            }
        }
    }
}

// ---------- fused per-node: logits + online softmax + aggregation ----------
// 2 waves per node (head-group g in {0,1}). Lane l owns 4 CONSECUTIVE
// channels g*256 + l*4 .. +3, all in head g*4 + (l>>4):
//  - gather = one packed ushort4 (8B bf16) per edge per lane; buffers stay
//    packed (16 VGPR for 8 edges) -> under the 64-VGPR occupancy cliff
//  - logit fold = in-lane dot of 4 + 16-lane DPP reduce (quad_perm xor1/xor2
//    + row_ror:4/:8) -> ZERO DS ops in the main loop
//  - softmax weight p lands in the lanes owning that head's channels:
//    no broadcasts; mh/sh/acc are plain per-lane state
//  - defer-rescale (THR=8): rescale only when mc > mh+8
// Tail edges masked via z=-1e30 (p=0); ssrc index clamped to beg.

#define LDCHUNK(cb, CX)                                                        \
  {                                                                            \
    int s0 = ssrc[(cb)];                                                       \
    int s1 = ssrc[((cb) + 1 < end) ? (cb) + 1 : beg];                          \
    int s2 = ssrc[((cb) + 2 < end) ? (cb) + 2 : beg];                          \
    int s3 = ssrc[((cb) + 3 < end) ? (cb) + 3 : beg];                          \
    CX[0] = *(const u16x4*)(XLg + (size_t)s0 * CH);                            \
    CX[1] = *(const u16x4*)(XLg + (size_t)s1 * CH);                            \
    CX[2] = *(const u16x4*)(XLg + (size_t)s2 * CH);                            \
    CX[3] = *(const u16x4*)(XLg + (size_t)s3 * CH);                            \
  }

#define PROCESS(CX, cb)                                                        \
  {                                                                            \
    float z[4];                                                                \
    _Pragma("unroll") for (int e = 0; e < 4; e++) {                            \
      float s = 0.f;                                                           \
      _Pragma("unroll") for (int r = 0; r < 4; r++) {                          \
        float t = bf16tof(CX[e][r]) + xrv[r];                                  \
        t = (t > 0.f) ? t : NEG * t;                                           \
        s += t * atv[r];                                                       \
      }                                                                        \
      z[e] = s;                                                                \
    }                                                                          \
    _Pragma("unroll") for (int e = 0; e < 4; e++) {                            \
      z[e] = dpp_add<0xB1>(z[e]);                                              \
      z[e] = dpp_add<0x4E>(z[e]);                                              \
      z[e] = dpp_add<0x124>(z[e]);                                             \
      z[e] = dpp_add<0x128>(z[e]);                                             \
    }                                                                          \
    _Pragma("unroll") for (int e = 1; e < 4; e++)                              \
      if ((cb) + e >= end) z[e] = -1e30f;                                      \
    float mc = fmaxf(fmaxf(z[0], z[1]), fmaxf(z[2], z[3]));                    \
    if (__ballot(mc > mh + 8.f) == 0ULL) {                                     \
      float p0 = __expf(z[0] - mh), p1 = __expf(z[1] - mh);                    \
      float p2 = __expf(z[2] - mh), p3 = __expf(z[3] - mh);                    \
      sh += (p0 + p1) + (p2 + p3);                                             \
      _Pragma("unroll") for (int r = 0; r < 4; r++)                            \
        acc[r] += p0 * bf16tof(CX[0][r]) + p1 * bf16tof(CX[1][r]) +            \
                  p2 * bf16tof(CX[2][r]) + p3 * bf16tof(CX[3][r]);             \
    } else {                                                                   \
      float nm = fmaxf(mh, mc);                                                \
      float sc = __expf(mh - nm);                                              \
      float p0 = __expf(z[0] - nm), p1 = __expf(z[1] - nm);                    \
      float p2 = __expf(z[2] - nm), p3 = __expf(z[3] - nm);                    \
      sh = sh * sc + (p0 + p1) + (p2 + p3);                                    \
      mh = nm;                                                                 \
      _Pragma("unroll") for (int r = 0; r < 4; r++)                            \
        acc[r] = acc[r] * sc + p0 * bf16tof(CX[0][r]) + p1 * bf16tof(CX[1][r]) \
                 + p2 * bf16tof(CX[2][r]) + p3 * bf16tof(CX[3][r]);            \
    }                                                                          \
  }

template <int WRITE_BF16>
__global__ __launch_bounds__(256) void k_node4(const unsigned short* __restrict__ XLb,
                                               const float* __restrict__ XR,
                                               const int* __restrict__ rowptr,
                                               const int* __restrict__ ssrc,
                                               const float* __restrict__ att,
                                               const float* __restrict__ bias,
                                               float* __restrict__ OUT,
                                               unsigned short* __restrict__ OAh) {
    int w = threadIdx.x >> 6;
    int n = blockIdx.x * 2 + (w >> 1);
    int g = w & 1;                       // head-group: heads g*4 .. g*4+3
    int l = threadIdx.x & 63;
    int beg = rowptr[n], end = rowptr[n + 1];
    int hb = g * 256 + l * 4;            // 4 consecutive channels, one head

    const unsigned short* XLg = XLb + hb;
    f32x4 xrv = *(const f32x4*)(XR + (size_t)n * CH + hb);
    f32x4 atv = *(const f32x4*)(att + hb);
    f32x4 acc = {0.f, 0.f, 0.f, 0.f};
    float mh = -1e30f, sh = 0.f;

    u16x4 curA[4], curB[4];
    LDCHUNK(beg, curA);
    int base = beg;
    while (true) {
        if (base + 4 < end) LDCHUNK(base + 4, curB);
        PROCESS(curA, base);
        base += 4;
        if (base >= end) break;
        if (base + 4 < end) LDCHUNK(base + 4, curA);
        PROCESS(curB, base);
        base += 4;
        if (base >= end) break;
    }

    float inv = 1.f / sh;
    f32x4 biasv = *(const f32x4*)(bias + hb);
    size_t ob = (size_t)n * CH + hb;
    if (WRITE_BF16) {
        u16x4 hv;
#pragma unroll
        for (int r = 0; r < 4; r++) {
            float wv = acc[r] * inv + biasv[r];
            hv[r] = bf16rne(wv);
        }
        *(u16x4*)(OAh + ob) = hv;
    } else {
        f32x4 ov;
#pragma unroll
        for (int r = 0; r < 4; r++) {
            float wv = acc[r] * inv + biasv[r];
            ov[r] = (wv > 0.f) ? wv : (__expf(wv) - 1.f);
        }
        *(f32x4*)(OUT + ob) = ov;
    }
}

// ---------- host ----------

extern "C" void kernel_launch(void* const* d_in, const int* in_sizes, int n_in,
                              void* d_out, int out_size, void* d_ws, size_t ws_size,
                              hipStream_t stream) {
    const float* x    = (const float*)d_in[0];
    const int*   ei   = (const int*)d_in[1];
    const float* W1l  = (const float*)d_in[2];
    const float* W1r  = (const float*)d_in[3];
    const float* att1 = (const float*)d_in[4];
    const float* b1   = (const float*)d_in[5];
    const float* W2l  = (const float*)d_in[6];
    const float* W2r  = (const float*)d_in[7];
    const float* att2 = (const float*)d_in[8];
    const float* b2   = (const float*)d_in[9];
    float* out = (float*)d_out;

    char* ws = (char*)d_ws;
    int* rowptr = (int*)ws;                 // NN+1
    int* cursor = rowptr + NN + 1;          // NN
    int* deg    = cursor + NN;              // NN
    int* ssrc   = deg + NN;                 // EPAD
    unsigned short* XLb = (unsigned short*)(((uintptr_t)(ssrc + EPAD) + 255) & ~(uintptr_t)255);
    float* XR = (float*)(XLb + (size_t)NN * CH);
    unsigned short* A_h = (unsigned short*)(XR + (size_t)NN * CH);  // NN*CH bf16
    unsigned short* W1h = A_h + (size_t)NN * CH;   // 1024*FIN
    unsigned short* W1o = W1h + 1024 * FIN;
    unsigned short* W2h = W1o + 1024 * FIN;        // 1024*CH
    unsigned short* W2o = W2h + 1024 * CH;

    hipMemsetAsync(cursor, 0, (size_t)2 * NN * sizeof(int), stream);
    k_deg<<<(EPAD + 255) / 256, 256, 0, stream>>>(ei, deg);
    k_scan<<<1, 1024, 0, stream>>>(deg, rowptr);
    k_scatter<<<(EPAD + 255) / 256, 256, 0, stream>>>(ei, rowptr, cursor, ssrc);
    k_cvt_w<FIN><<<1024 * FIN / 256, 256, 0, stream>>>(W1l, W1r, W1h, W1o);
    k_cvt_w<CH><<<1024 * CH / 256, 256, 0, stream>>>(W2l, W2r, W2h, W2o);

    for (int b = 0; b < 2; b++) {
        const float* f = x + (size_t)b * NN * FIN;
        k_cvt_ah<<<NN * FIN / 4 / 256, 256, 0, stream>>>(f, A_h, NN * FIN / 4);
        k_gemm_mfma<FIN><<<dim3(NN / 128, 8), 256, 0, stream>>>(A_h, W1h, W1o, XLb, XR);
        k_node4<1><<<NN / 2, 256, 0, stream>>>(XLb, XR, rowptr, ssrc, att1, b1, nullptr, A_h);
        k_gemm_mfma<CH><<<dim3(NN / 128, 8), 256, 0, stream>>>(A_h, W2h, W2o, XLb, XR);
        k_node4<0><<<NN / 2, 256, 0, stream>>>(XLb, XR, rowptr, ssrc, att2, b2,
                                               out + (size_t)b * NN * CH, nullptr);
    }
}

// Round 12
// 252.197 us; speedup vs baseline: 1.4980x; 1.1579x over previous
//
#include <hip/hip_runtime.h>
#include <cstdint>

#define NN 8192
#define NT 16384         // 2 batches merged: total rows
#define EE 131072
#define EPAD (EE + NN)   // edges + self loops = 139264
#define SPAD (EPAD + 3 * NN)  // 4-aligned padded CSR capacity
#define FIN 128
#define CH 512           // H*HID = H*OUT
#define NH 8
#define NEG 0.2f

typedef __attribute__((ext_vector_type(8))) short short8;
typedef __attribute__((ext_vector_type(4))) unsigned short u16x4;
typedef __attribute__((ext_vector_type(4))) float f32x4;
typedef __attribute__((ext_vector_type(4))) int i32x4;

__device__ inline unsigned short bf16rne(float x) {
    unsigned u = __float_as_uint(x);
    unsigned r = (u + 0x7FFFu + ((u >> 16) & 1u)) >> 16;
    return (unsigned short)r;
}
__device__ inline float bf16tof(unsigned short h) {
    return __uint_as_float((unsigned)h << 16);
}
__device__ inline void gload16(const void* g, void* l) {
    __builtin_amdgcn_global_load_lds((const __attribute__((address_space(1))) void*)g,
                                     (__attribute__((address_space(3))) void*)l, 16, 0, 0);
}
// cross-lane add via DPP (VALU only, no DS crossbar). CTRL: 0xB1=quad_perm
// xor1, 0x4E=quad_perm xor2, 0x124=row_ror:4, 0x128=row_ror:8.
template <int CTRL>
__device__ inline float dpp_add(float x) {
    int v = __builtin_amdgcn_update_dpp(0, __float_as_int(x), CTRL, 0xF, 0xF, true);
    return x + __int_as_float(v);
}

// ---------- CSR build (4-aligned padded segments) ----------

__global__ __launch_bounds__(256) void k_deg(const int* __restrict__ ei, int* __restrict__ deg) {
    int e = blockIdx.x * 256 + threadIdx.x;
    if (e >= EPAD) return;
    int dst = (e < EE) ? ei[EE + e] : (e - EE);
    atomicAdd(&deg[dst], 1);
}

__global__ __launch_bounds__(1024) void k_scan(const int* __restrict__ deg, int* __restrict__ rowptr) {
    __shared__ int part[1024];
    int t = threadIdx.x;
    int loc[8];
    int s = 0;
#pragma unroll
    for (int i = 0; i < 8; i++) { loc[i] = s; s += (deg[t * 8 + i] + 3) & ~3; }
    part[t] = s;
    __syncthreads();
    if (t == 0) {
        int run = 0;
        for (int i = 0; i < 1024; i++) { int tmp = part[i]; part[i] = run; run += tmp; }
        rowptr[NN] = run;
    }
    __syncthreads();
    int base = part[t];
#pragma unroll
    for (int i = 0; i < 8; i++) rowptr[t * 8 + i] = base + loc[i];
}

__global__ __launch_bounds__(256) void k_scatter(const int* __restrict__ ei, const int* __restrict__ rowptr,
                                                 int* __restrict__ cursor, int* __restrict__ ssrc) {
    int e = blockIdx.x * 256 + threadIdx.x;
    if (e >= EPAD) return;
    int src = (e < EE) ? ei[e] : (e - EE);
    int dst = (e < EE) ? ei[EE + e] : (e - EE);
    int pos = rowptr[dst] + atomicAdd(&cursor[dst], 1);
    ssrc[pos] = src;
}

// fill pad slots with src=0 (row 0 gather, masked out of softmax)
__global__ __launch_bounds__(256) void k_pad(const int* __restrict__ rowptr, const int* __restrict__ deg,
                                             int* __restrict__ ssrc) {
    int n = blockIdx.x * 256 + threadIdx.x;
    if (n >= NN) return;
    int e = rowptr[n] + deg[n], pe = rowptr[n + 1];
    for (int i = e; i < pe; i++) ssrc[i] = 0;
}

// ---------- conversions ----------

__global__ __launch_bounds__(256) void k_cvt_ah(const float* __restrict__ F,
                                                unsigned short* __restrict__ Ah, int n4) {
    int i = blockIdx.x * 256 + threadIdx.x;
    if (i >= n4) return;
    f32x4 v = ((const f32x4*)F)[i];
#pragma unroll
    for (int c = 0; c < 4; c++) Ah[i * 4 + c] = bf16rne(v[c]);
}

// W[K][512] (Wl,Wr) -> Wt[n=1024][K] hi/lo (transposed, K contiguous)
template <int K>
__global__ __launch_bounds__(256) void k_cvt_w(const float* __restrict__ Wl, const float* __restrict__ Wr,
                                               unsigned short* __restrict__ Wh, unsigned short* __restrict__ Wlo) {
    int idx = blockIdx.x * 256 + threadIdx.x;   // = n*K + k
    int n = idx / K, k = idx % K;
    const float* W = (n < 512) ? Wl : Wr;
    float x = W[k * 512 + (n & 511)];
    unsigned short h = bf16rne(x);
    Wh[idx] = h;
    Wlo[idx] = bf16rne(x - bf16tof(h));
}

// ---------- split-bf16 MFMA GEMM: [NT x K] @ [K x 1024] -> XLb (bf16) | XR (f32) ----------
// A in bf16-hi only; B in hi+lo (2 MFMA/frag): Ah*(Bh+Bl) ~ A_fp32 * B_fp32.

template <int K>
__global__ __launch_bounds__(256) void k_gemm_mfma(const unsigned short* __restrict__ Ah,
                                                   const unsigned short* __restrict__ Bh,
                                                   const unsigned short* __restrict__ Bl,
                                                   unsigned short* __restrict__ XLb,
                                                   float* __restrict__ XR) {
    __shared__ unsigned short sAh[4][128][8], sBh[4][128][8], sBl[4][128][8];
    int tid = threadIdx.x;
    int l = tid & 63;
    int w = tid >> 6, wm = w >> 1, wn = w & 1;
    int m0 = blockIdx.x * 128, n0 = blockIdx.y * 128;
    int lr = l & 15, kh = l >> 4;
    f32x4 acc[4][4] = {};

    for (int k0 = 0; k0 < K; k0 += 32) {
#pragma unroll
        for (int g = 0; g < 2; g++) {
            int cell = g * 256 + tid;
            int ckh = cell >> 7, cr = cell & 127;
            int ka = k0 + ckh * 8;
            gload16(Ah + (size_t)(m0 + cr) * K + ka, &sAh[ckh][cr][0]);
            gload16(Bh + (size_t)(n0 + cr) * K + ka, &sBh[ckh][cr][0]);
            gload16(Bl + (size_t)(n0 + cr) * K + ka, &sBl[ckh][cr][0]);
        }
        __syncthreads();
        short8 fah[4], fbh[4], fbl[4];
#pragma unroll
        for (int i = 0; i < 4; i++) {
            fah[i] = *(const short8*)&sAh[kh][wm * 64 + i * 16 + lr][0];
            fbh[i] = *(const short8*)&sBh[kh][wn * 64 + i * 16 + lr][0];
            fbl[i] = *(const short8*)&sBl[kh][wn * 64 + i * 16 + lr][0];
        }
#pragma unroll
        for (int i = 0; i < 4; i++)
#pragma unroll
            for (int j = 0; j < 4; j++) {
                acc[i][j] = __builtin_amdgcn_mfma_f32_16x16x32_bf16(fah[i], fbl[j], acc[i][j], 0, 0, 0);
                acc[i][j] = __builtin_amdgcn_mfma_f32_16x16x32_bf16(fah[i], fbh[j], acc[i][j], 0, 0, 0);
            }
        __syncthreads();
    }
    // C/D layout: col = lane&15, row = (lane>>4)*4 + q  [m89-verified]
    int colt = n0 + wn * 64;     // wave-uniform
    int cb = colt & 511;
    if (colt < 512) {
#pragma unroll
        for (int i = 0; i < 4; i++) {
            int mg = m0 + wm * 64 + i * 16 + kh * 4;
#pragma unroll
            for (int j = 0; j < 4; j++) {
                int cg = cb + j * 16 + lr;
#pragma unroll
                for (int q = 0; q < 4; q++)
                    XLb[(size_t)(mg + q) * CH + cg] = bf16rne(acc[i][j][q]);
            }
        }
    } else {
#pragma unroll
        for (int i = 0; i < 4; i++) {
            int mg = m0 + wm * 64 + i * 16 + kh * 4;
#pragma unroll
            for (int j = 0; j < 4; j++) {
                int cg = cb + j * 16 + lr;
#pragma unroll
                for (int q = 0; q < 4; q++)
                    XR[(size_t)(mg + q) * CH + cg] = acc[i][j][q];
            }
        }
    }
}

// ---------- fused per-node: logits + online softmax + aggregation ----------
// Both batches in one launch (nid in [0,16384); node = nid&8191, batch =
// nid>>13). 2 waves per node (head-group g in {0,1}); lane l owns 4
// consecutive channels g*256+l*4.. (one head). 4-edge chunks, double-
// buffered; padded CSR -> chunk indices via ONE int4 load; packed bf16
// gathers; DPP-only logit fold; per-lane softmax state; defer-rescale THR=8.
// Tail/pad edges masked via z=-1e30 (p=0); pad slots read row 0 (valid).

#define LDCHUNK(cb, CX)                                                        \
  {                                                                            \
    i32x4 sv = *(const i32x4*)(ssrc + (cb));                                   \
    CX[0] = *(const u16x4*)(XLg + (size_t)sv[0] * CH);                         \
    CX[1] = *(const u16x4*)(XLg + (size_t)sv[1] * CH);                         \
    CX[2] = *(const u16x4*)(XLg + (size_t)sv[2] * CH);                         \
    CX[3] = *(const u16x4*)(XLg + (size_t)sv[3] * CH);                         \
  }

#define PROCESS(CX, cb)                                                        \
  {                                                                            \
    float z[4];                                                                \
    _Pragma("unroll") for (int e = 0; e < 4; e++) {                            \
      float s = 0.f;                                                           \
      _Pragma("unroll") for (int r = 0; r < 4; r++) {                          \
        float t = bf16tof(CX[e][r]) + xrv[r];                                  \
        t = (t > 0.f) ? t : NEG * t;                                           \
        s += t * atv[r];                                                       \
      }                                                                        \
      z[e] = s;                                                                \
    }                                                                          \
    _Pragma("unroll") for (int e = 0; e < 4; e++) {                            \
      z[e] = dpp_add<0xB1>(z[e]);                                              \
      z[e] = dpp_add<0x4E>(z[e]);                                              \
      z[e] = dpp_add<0x124>(z[e]);                                             \
      z[e] = dpp_add<0x128>(z[e]);                                             \
    }                                                                          \
    _Pragma("unroll") for (int e = 1; e < 4; e++)                              \
      if ((cb) + e >= end) z[e] = -1e30f;                                      \
    float mc = fmaxf(fmaxf(z[0], z[1]), fmaxf(z[2], z[3]));                    \
    if (__ballot(mc > mh + 8.f) == 0ULL) {                                     \
      float p0 = __expf(z[0] - mh), p1 = __expf(z[1] - mh);                    \
      float p2 = __expf(z[2] - mh), p3 = __expf(z[3] - mh);                    \
      sh += (p0 + p1) + (p2 + p3);                                             \
      _Pragma("unroll") for (int r = 0; r < 4; r++)                            \
        acc[r] += p0 * bf16tof(CX[0][r]) + p1 * bf16tof(CX[1][r]) +            \
                  p2 * bf16tof(CX[2][r]) + p3 * bf16tof(CX[3][r]);             \
    } else {                                                                   \
      float nm = fmaxf(mh, mc);                                                \
      float sc = __expf(mh - nm);                                              \
      float p0 = __expf(z[0] - nm), p1 = __expf(z[1] - nm);                    \
      float p2 = __expf(z[2] - nm), p3 = __expf(z[3] - nm);                    \
      sh = sh * sc + (p0 + p1) + (p2 + p3);                                    \
      mh = nm;                                                                 \
      _Pragma("unroll") for (int r = 0; r < 4; r++)                            \
        acc[r] = acc[r] * sc + p0 * bf16tof(CX[0][r]) + p1 * bf16tof(CX[1][r]) \
                 + p2 * bf16tof(CX[2][r]) + p3 * bf16tof(CX[3][r]);            \
    }                                                                          \
  }

template <int WRITE_BF16>
__global__ __launch_bounds__(256) void k_node5(const unsigned short* __restrict__ XLb,
                                               const float* __restrict__ XR,
                                               const int* __restrict__ rowptr,
                                               const int* __restrict__ deg,
                                               const int* __restrict__ ssrc,
                                               const float* __restrict__ att,
                                               const float* __restrict__ bias,
                                               float* __restrict__ OUT,
                                               unsigned short* __restrict__ OAh) {
    int w = threadIdx.x >> 6;
    int nid = blockIdx.x * 2 + (w >> 1);   // global row 0..NT-1
    int g = w & 1;                         // head-group: heads g*4 .. g*4+3
    int l = threadIdx.x & 63;
    int node = nid & (NN - 1);
    int beg = rowptr[node], end = beg + deg[node];
    int hb = g * 256 + l * 4;              // 4 consecutive channels, one head

    const unsigned short* XLg = XLb + (size_t)(nid >> 13) * NN * CH + hb;
    f32x4 xrv = *(const f32x4*)(XR + (size_t)nid * CH + hb);
    f32x4 atv = *(const f32x4*)(att + hb);
    f32x4 acc = {0.f, 0.f, 0.f, 0.f};
    float mh = -1e30f, sh = 0.f;

    u16x4 curA[4], curB[4];
    LDCHUNK(beg, curA);
    int base = beg;
    while (true) {
        if (base + 4 < end) LDCHUNK(base + 4, curB);
        PROCESS(curA, base);
        base += 4;
        if (base >= end) break;
        if (base + 4 < end) LDCHUNK(base + 4, curA);
        PROCESS(curB, base);
        base += 4;
        if (base >= end) break;
    }

    float inv = 1.f / sh;
    f32x4 biasv = *(const f32x4*)(bias + hb);
    size_t ob = (size_t)nid * CH + hb;
    if (WRITE_BF16) {
        u16x4 hv;
#pragma unroll
        for (int r = 0; r < 4; r++) {
            float wv = acc[r] * inv + biasv[r];
            hv[r] = bf16rne(wv);
        }
        *(u16x4*)(OAh + ob) = hv;
    } else {
        f32x4 ov;
#pragma unroll
        for (int r = 0; r < 4; r++) {
            float wv = acc[r] * inv + biasv[r];
            ov[r] = (wv > 0.f) ? wv : (__expf(wv) - 1.f);
        }
        *(f32x4*)(OUT + ob) = ov;
    }
}

// ---------- host ----------

extern "C" void kernel_launch(void* const* d_in, const int* in_sizes, int n_in,
                              void* d_out, int out_size, void* d_ws, size_t ws_size,
                              hipStream_t stream) {
    const float* x    = (const float*)d_in[0];
    const int*   ei   = (const int*)d_in[1];
    const float* W1l  = (const float*)d_in[2];
    const float* W1r  = (const float*)d_in[3];
    const float* att1 = (const float*)d_in[4];
    const float* b1   = (const float*)d_in[5];
    const float* W2l  = (const float*)d_in[6];
    const float* W2r  = (const float*)d_in[7];
    const float* att2 = (const float*)d_in[8];
    const float* b2   = (const float*)d_in[9];
    float* out = (float*)d_out;

    char* ws = (char*)d_ws;
    int* rowptr = (int*)ws;                 // NN+1
    int* cursor = rowptr + NN + 1;          // NN
    int* deg    = cursor + NN;              // NN
    int* ssrc   = deg + NN;                 // SPAD (4-aligned padded)
    unsigned short* XLb = (unsigned short*)(((uintptr_t)(ssrc + SPAD) + 255) & ~(uintptr_t)255);
    float* XR = (float*)(XLb + (size_t)NT * CH);
    unsigned short* A_h = (unsigned short*)(XR + (size_t)NT * CH);  // NT*CH bf16
    unsigned short* W1h = A_h + (size_t)NT * CH;   // 1024*FIN
    unsigned short* W1o = W1h + 1024 * FIN;
    unsigned short* W2h = W1o + 1024 * FIN;        // 1024*CH
    unsigned short* W2o = W2h + 1024 * CH;

    hipMemsetAsync(cursor, 0, (size_t)2 * NN * sizeof(int), stream);
    k_deg<<<(EPAD + 255) / 256, 256, 0, stream>>>(ei, deg);
    k_scan<<<1, 1024, 0, stream>>>(deg, rowptr);
    k_scatter<<<(EPAD + 255) / 256, 256, 0, stream>>>(ei, rowptr, cursor, ssrc);
    k_pad<<<NN / 256, 256, 0, stream>>>(rowptr, deg, ssrc);
    k_cvt_w<FIN><<<1024 * FIN / 256, 256, 0, stream>>>(W1l, W1r, W1h, W1o);
    k_cvt_w<CH><<<1024 * CH / 256, 256, 0, stream>>>(W2l, W2r, W2h, W2o);

    // layer 1 (both batches merged: NT rows)
    k_cvt_ah<<<NT * FIN / 4 / 256, 256, 0, stream>>>(x, A_h, NT * FIN / 4);
    k_gemm_mfma<FIN><<<dim3(NT / 128, 8), 256, 0, stream>>>(A_h, W1h, W1o, XLb, XR);
    k_node5<1><<<NT / 2, 256, 0, stream>>>(XLb, XR, rowptr, deg, ssrc, att1, b1, nullptr, A_h);
    // layer 2
    k_gemm_mfma<CH><<<dim3(NT / 128, 8), 256, 0, stream>>>(A_h, W2h, W2o, XLb, XR);
    k_node5<0><<<NT / 2, 256, 0, stream>>>(XLb, XR, rowptr, deg, ssrc, att2, b2, out, nullptr);
}